// Round 7
// baseline (317.508 us; speedup 1.0000x reference)
//
#include <hip/hip_runtime.h>

// BinsChamferLoss — register-resident chamfer with cross-lane rotation.
// L=4 scales, N=4 batch, P=256 centers, M=76800 y per batch element.
//
// Rounds 4/6: LDS-broadcast and SGPR-stream both stuck at ~55 µs, VALUBusy
// ~40% — each 16-value stream window ends in a dependent waitcnt; waves
// convoy. Fix: NO memory in the hot loop. One wave holds ALL 256 centers
// per scale stationary in VGPRs (4/lane x 64 lanes x 4 scales = 16 regs);
// a packet {y, mb[0..3]} rotates lane->lane+1 via ds_bpermute each step.
// After 64 steps each y has met all 256 centers of every scale:
//   direction B: mb travels with its y  (complete, no cross-wave merge)
//   direction A: ma[l][k] stationary    (atomicMin merge across waves)
// The SAME d = ca - y feeds both directions -> unique pairs halved.
// fminf(fminf(x,|a|),|b|) -> v_min3_f32 with abs input modifiers.
// Squaring after the |.|-min is bitwise min-of-squares (RN monotone on |x|).

#define NSCALES 4
#define NBATCH  4
#define NEDGES  257
#define NP      256
#define NM      76800
#define BLOCK   256
#define WPN     (NM / 64)             // 1200 waves per batch element
#define NBLK    (NBATCH * WPN / 4)    // 1200 blocks of 4 independent waves
#define NLN     (NSCALES * NBATCH)    // 16
#define BIGF    1e10f
#define SENT    3e9f

// ws float-offsets (mutually disjoint)
#define WS_MIN  0                     // [16*256] minabs (rw)
#define WS_SUMY 4096                  // [16]
#define WS_CNT  4112                  // [4] uint

__global__ __launch_bounds__(BLOCK) void bcl_init(float* __restrict__ ws) {
    const int t = blockIdx.x * BLOCK + threadIdx.x;
    if (t < NLN * NP) ws[WS_MIN + t] = BIGF;
    if (t < NLN)      ws[WS_SUMY + t] = 0.0f;
    if (t < NBATCH)   ((unsigned int*)ws)[WS_CNT + t] = 0u;
}

__device__ __forceinline__ float rot1(float v, int pidx) {
    return __int_as_float(__builtin_amdgcn_ds_bpermute(pidx, __float_as_int(v)));
}

__global__ __launch_bounds__(BLOCK) void bcl_main(const float* __restrict__ bins,
                                                  const float* __restrict__ depth,
                                                  float* __restrict__ minabs,
                                                  float* __restrict__ sumy,
                                                  unsigned int* __restrict__ cnt) {
    const int lane = threadIdx.x & 63;
    const int wv   = threadIdx.x >> 6;
    const int gw   = blockIdx.x * 4 + wv;     // global wave id, 0..4799
    const int n    = gw / WPN;                // batch element
    const int yg   = gw - n * WPN;            // 64-y group within batch elem

    // stationary: all 256 centers of each scale, 4 per lane; accumulators
    float ca[NSCALES][4], ma[NSCALES][4];
#pragma unroll
    for (int l = 0; l < NSCALES; ++l) {
        const float* e = bins + (l * NBATCH + n) * NEDGES;
#pragma unroll
        for (int k = 0; k < 4; ++k) {
            const int p = lane + 64 * k;
            ca[l][k] = 0.5f * (e[p] + e[p + 1]);
            ma[l][k] = BIGF;
        }
    }

    // traveling packet: own y (sentineled) + per-scale running min
    const float yraw = depth[n * NM + yg * 64 + lane];
    const bool valid = (yraw >= 0.001f);
    float y = valid ? yraw : SENT;
    float mb[NSCALES];
#pragma unroll
    for (int l = 0; l < NSCALES; ++l) mb[l] = BIGF;

    const int pidx = ((lane + 63) & 63) * 4;  // pull from lane-1 => packets move +1

#pragma unroll 2
    for (int it = 0; it < 32; ++it) {
        // ---- step A: rotate packet in, compute d, update traveling mb ----
        y = rot1(y, pidx);
#pragma unroll
        for (int l = 0; l < NSCALES; ++l) mb[l] = rot1(mb[l], pidx);
        float dA[NSCALES][4];
#pragma unroll
        for (int l = 0; l < NSCALES; ++l) {
#pragma unroll
            for (int k = 0; k < 4; ++k) dA[l][k] = ca[l][k] - y;
            mb[l] = fminf(fminf(mb[l], fabsf(dA[l][0])), fabsf(dA[l][1]));
            mb[l] = fminf(fminf(mb[l], fabsf(dA[l][2])), fabsf(dA[l][3]));
        }
        // ---- step B: rotate again; update mb and fold BOTH steps into ma ----
        y = rot1(y, pidx);
#pragma unroll
        for (int l = 0; l < NSCALES; ++l) mb[l] = rot1(mb[l], pidx);
#pragma unroll
        for (int l = 0; l < NSCALES; ++l) {
            const float dB0 = ca[l][0] - y, dB1 = ca[l][1] - y;
            const float dB2 = ca[l][2] - y, dB3 = ca[l][3] - y;
            mb[l] = fminf(fminf(mb[l], fabsf(dB0)), fabsf(dB1));
            mb[l] = fminf(fminf(mb[l], fabsf(dB2)), fabsf(dB3));
            ma[l][0] = fminf(fminf(ma[l][0], fabsf(dA[l][0])), fabsf(dB0));
            ma[l][1] = fminf(fminf(ma[l][1], fabsf(dA[l][1])), fabsf(dB1));
            ma[l][2] = fminf(fminf(ma[l][2], fabsf(dA[l][2])), fabsf(dB2));
            ma[l][3] = fminf(fminf(ma[l][3], fabsf(dA[l][3])), fabsf(dB3));
        }
    }
    // 64 rotations = identity: mb is home, paired with this lane's own y

    // ---- direction A merge (non-negative floats: int min == float min) ----
#pragma unroll
    for (int l = 0; l < NSCALES; ++l)
#pragma unroll
        for (int k = 0; k < 4; ++k)
            atomicMin(((int*)minabs) + (l * NBATCH + n) * NP + lane + 64 * k,
                      __float_as_int(ma[l][k]));

    // ---- direction B: per-wave shuffle reduce, one atomic per wave ----
    float suml[NSCALES];
#pragma unroll
    for (int l = 0; l < NSCALES; ++l) suml[l] = valid ? mb[l] * mb[l] : 0.0f;
#pragma unroll
    for (int off = 32; off; off >>= 1)
#pragma unroll
        for (int l = 0; l < NSCALES; ++l) suml[l] += __shfl_down(suml[l], off);
    const unsigned long long bal = __ballot(valid);
    if (lane == 0) {
#pragma unroll
        for (int l = 0; l < NSCALES; ++l) atomicAdd(&sumy[l * NBATCH + n], suml[l]);
        atomicAdd(&cnt[n], (unsigned int)__popcll(bal));
    }
}

__global__ __launch_bounds__(BLOCK) void bcl_final(const float* __restrict__ minabs,
                                                   const float* __restrict__ sumy,
                                                   const unsigned int* __restrict__ cnt,
                                                   float* __restrict__ out) {
    __shared__ float red[BLOCK / 64];
    const int t = threadIdx.x;
    float s = 0.0f;
#pragma unroll
    for (int k = 0; k < NLN; ++k) {
        const float m = minabs[t + k * BLOCK];
        s += m * m;
    }
#pragma unroll
    for (int off = 32; off; off >>= 1) s += __shfl_down(s, off);
    if ((t & 63) == 0) red[t >> 6] = s;
    __syncthreads();
    if (t == 0) {
        const float S = red[0] + red[1] + red[2] + red[3];   // sum of minx^2
        float lossB = 0.0f;
#pragma unroll
        for (int i = 0; i < NLN; ++i)
            lossB += sumy[i] / (float)cnt[i & (NBATCH - 1)];
        out[0] = (S / (float)NP + lossB) / (float)NBATCH;
    }
}

extern "C" void kernel_launch(void* const* d_in, const int* in_sizes, int n_in,
                              void* d_out, int out_size, void* d_ws, size_t ws_size,
                              hipStream_t stream) {
    const float* bins  = (const float*)d_in[0];   // [4,4,257] f32
    const float* depth = (const float*)d_in[1];   // [4,240,320] f32
    float* ws = (float*)d_ws;

    float* minabs = ws + WS_MIN;
    float* sumy   = ws + WS_SUMY;
    unsigned int* cnt = (unsigned int*)ws + WS_CNT;

    bcl_init <<<NLN * NP / BLOCK, BLOCK, 0, stream>>>(ws);
    bcl_main <<<NBLK,             BLOCK, 0, stream>>>(bins, depth, minabs, sumy, cnt);
    bcl_final<<<1,                BLOCK, 0, stream>>>(minabs, sumy, cnt, (float*)d_out);
}

// Round 8
// 119.198 us; speedup vs baseline: 2.6637x; 2.6637x over previous
//
#include <hip/hip_runtime.h>

// BinsChamferLoss — two VALU-dense brute-force passes.
// L=4 scales, N=4 batch, P=256 centers, M=76800 y per batch element.
//
// Round-4/6 diagnosis (arithmetic from m134's ds_read_b128 ~12cy/instr):
// 320 LDS instrs/thread serialized the per-CU LDS pipe (~30 µs), VALU only
// 43%. Round-7 rotation spilled registers (20 MB scratch writes). Fix:
// maximize VALU per LDS instruction (1 ds_read_b128 -> 24 VALU) and keep
// per-thread state small (~30 VGPR):
//   Kernel A (x->y): thread owns 4 centers (regs), streams 256 sentineled
//     y from LDS float4; atomicMin-merge (pre-filtered) into ws.
//   Kernel B (y->x): thread owns 4 y (coalesced float4 global load, no LDS),
//     streams one scale's 256 centers from LDS float4; complete per-thread
//     min -> wave reduce -> one atomicAdd per wave.
// Both: 1200 blocks x 4 waves = 4800 waves (4.7/SIMD), manual cur/nxt
// prefetch, fminf(fminf(x,|a|),|b|) -> v_min3_f32 with free abs modifiers.
// Squaring after the |.|-min equals min-of-squares (RN monotone on |x|).

#define NSCALES 4
#define NBATCH  4
#define NEDGES  257
#define NP      256
#define NM      76800
#define BLOCK   256
#define ACHUNK  256                   // y per A-block
#define ANCH    (NM / ACHUNK)         // 300 chunks per n
#define BGRP    1024                  // y per B-block
#define BNG     (NM / BGRP)           // 75 groups per n
#define NLN     (NSCALES * NBATCH)    // 16
#define BIGF    1e10f
#define SENT    3e9f

// ws float-offsets (disjoint)
#define WS_MIN  0                     // [16*256] minabs (rw)
#define WS_SUMY 4096                  // [16]
#define WS_CNT  4112                  // [4] uint

__global__ __launch_bounds__(BLOCK) void bcl_init(float* __restrict__ ws) {
    const int t = blockIdx.x * BLOCK + threadIdx.x;
    if (t < NLN * NP) ws[WS_MIN + t] = BIGF;
    if (t < NLN)      ws[WS_SUMY + t] = 0.0f;
    if (t < NBATCH)   ((unsigned int*)ws)[WS_CNT + t] = 0u;
}

// ---------------- direction A: centers stationary, y streamed ----------------
__global__ __launch_bounds__(BLOCK) void bcl_a(const float* __restrict__ bins,
                                               const float* __restrict__ depth,
                                               float* __restrict__ minabs) {
    __shared__ float sY[ACHUNK];
    const int b = blockIdx.x;             // 1200 = n(4) x chunk(300)
    const int n = b / ANCH;
    const int chunk = b - n * ANCH;
    const int t = threadIdx.x;

    {   // stage sentineled y (1 per thread)
        const float v = depth[n * NM + chunk * ACHUNK + t];
        sY[t] = (v >= 0.001f) ? v : SENT;
    }
    float ca[NSCALES], ma[NSCALES];
#pragma unroll
    for (int l = 0; l < NSCALES; ++l) {
        const float* e = bins + (l * NBATCH + n) * NEDGES + t;
        ca[l] = 0.5f * (e[0] + e[1]);     // own center p=t of scale l
        ma[l] = BIGF;
    }
    __syncthreads();

    const float4* sY4 = (const float4*)sY;
    float4 cur = sY4[0];
#pragma unroll 4
    for (int w = 0; w < ACHUNK / 4 - 1; ++w) {
        const float4 nxt = sY4[w + 1];    // prefetch: waitcnt lands after compute
#pragma unroll
        for (int l = 0; l < NSCALES; ++l) {
            ma[l] = fminf(fminf(ma[l], fabsf(ca[l] - cur.x)), fabsf(ca[l] - cur.y));
            ma[l] = fminf(fminf(ma[l], fabsf(ca[l] - cur.z)), fabsf(ca[l] - cur.w));
        }
        cur = nxt;
    }
#pragma unroll
    for (int l = 0; l < NSCALES; ++l) {
        ma[l] = fminf(fminf(ma[l], fabsf(ca[l] - cur.x)), fabsf(ca[l] - cur.y));
        ma[l] = fminf(fminf(ma[l], fabsf(ca[l] - cur.z)), fabsf(ca[l] - cur.w));
    }
    // pre-filtered merge; int min == float min for non-negative floats
#pragma unroll
    for (int l = 0; l < NSCALES; ++l) {
        const int idx = (l * NBATCH + n) * NP + t;
        if (ma[l] < minabs[idx])
            atomicMin((int*)minabs + idx, __float_as_int(ma[l]));
    }
}

// ---------------- direction B: y stationary, centers streamed ----------------
__global__ __launch_bounds__(BLOCK) void bcl_b(const float* __restrict__ bins,
                                               const float* __restrict__ depth,
                                               float* __restrict__ sumy,
                                               unsigned int* __restrict__ cnt) {
    __shared__ float sC[NP];
    __shared__ float redS[BLOCK / 64];
    __shared__ unsigned int redC[BLOCK / 64];
    const int b = blockIdx.x;             // 1200 = n(4) x l(4) x g(75)
    const int n = b / (NSCALES * BNG);
    const int r = b - n * (NSCALES * BNG);
    const int l = r / BNG;
    const int g = r - l * BNG;
    const int t = threadIdx.x;

    {   // stage this (l,n)'s 256 centers (1 per thread)
        const float* e = bins + (l * NBATCH + n) * NEDGES + t;
        sC[t] = 0.5f * (e[0] + e[1]);
    }
    // own 4 y, coalesced 16B load
    const float4 yv = *(const float4*)(depth + n * NM + g * BGRP + t * 4);
    const bool v0 = yv.x >= 0.001f, v1 = yv.y >= 0.001f;
    const bool v2 = yv.z >= 0.001f, v3 = yv.w >= 0.001f;
    float m0 = BIGF, m1 = BIGF, m2 = BIGF, m3 = BIGF;
    __syncthreads();

    const float4* sC4 = (const float4*)sC;
    float4 cur = sC4[0];
#pragma unroll 4
    for (int w = 0; w < NP / 4 - 1; ++w) {
        const float4 nxt = sC4[w + 1];
        m0 = fminf(fminf(m0, fabsf(cur.x - yv.x)), fabsf(cur.y - yv.x));
        m0 = fminf(fminf(m0, fabsf(cur.z - yv.x)), fabsf(cur.w - yv.x));
        m1 = fminf(fminf(m1, fabsf(cur.x - yv.y)), fabsf(cur.y - yv.y));
        m1 = fminf(fminf(m1, fabsf(cur.z - yv.y)), fabsf(cur.w - yv.y));
        m2 = fminf(fminf(m2, fabsf(cur.x - yv.z)), fabsf(cur.y - yv.z));
        m2 = fminf(fminf(m2, fabsf(cur.z - yv.z)), fabsf(cur.w - yv.z));
        m3 = fminf(fminf(m3, fabsf(cur.x - yv.w)), fabsf(cur.y - yv.w));
        m3 = fminf(fminf(m3, fabsf(cur.z - yv.w)), fabsf(cur.w - yv.w));
        cur = nxt;
    }
    m0 = fminf(fminf(m0, fabsf(cur.x - yv.x)), fabsf(cur.y - yv.x));
    m0 = fminf(fminf(m0, fabsf(cur.z - yv.x)), fabsf(cur.w - yv.x));
    m1 = fminf(fminf(m1, fabsf(cur.x - yv.y)), fabsf(cur.y - yv.y));
    m1 = fminf(fminf(m1, fabsf(cur.z - yv.y)), fabsf(cur.w - yv.y));
    m2 = fminf(fminf(m2, fabsf(cur.x - yv.z)), fabsf(cur.y - yv.z));
    m2 = fminf(fminf(m2, fabsf(cur.z - yv.z)), fabsf(cur.w - yv.z));
    m3 = fminf(fminf(m3, fabsf(cur.x - yv.w)), fabsf(cur.y - yv.w));
    m3 = fminf(fminf(m3, fabsf(cur.z - yv.w)), fabsf(cur.w - yv.w));

    float suml = (v0 ? m0 * m0 : 0.0f) + (v1 ? m1 * m1 : 0.0f)
               + (v2 ? m2 * m2 : 0.0f) + (v3 ? m3 * m3 : 0.0f);
    unsigned int cc = (v0 ? 1u : 0u) + (v1 ? 1u : 0u) + (v2 ? 1u : 0u) + (v3 ? 1u : 0u);

#pragma unroll
    for (int off = 32; off; off >>= 1) {
        suml += __shfl_down(suml, off);
        cc   += __shfl_down(cc, off);
    }
    const int wv = t >> 6;
    if ((t & 63) == 0) { redS[wv] = suml; redC[wv] = cc; }
    __syncthreads();
    if (t == 0) {
        atomicAdd(&sumy[l * NBATCH + n], redS[0] + redS[1] + redS[2] + redS[3]);
        if (l == 0)
            atomicAdd(&cnt[n], redC[0] + redC[1] + redC[2] + redC[3]);
    }
}

__global__ __launch_bounds__(BLOCK) void bcl_final(const float* __restrict__ ws,
                                                   float* __restrict__ out) {
    __shared__ float red[BLOCK / 64];
    const int t = threadIdx.x;
    float s = 0.0f;
#pragma unroll
    for (int k = 0; k < NLN; ++k) {
        const float m = ws[WS_MIN + t + k * BLOCK];
        s += m * m;
    }
#pragma unroll
    for (int off = 32; off; off >>= 1) s += __shfl_down(s, off);
    if ((t & 63) == 0) red[t >> 6] = s;
    __syncthreads();
    if (t == 0) {
        const float S = red[0] + red[1] + red[2] + red[3];   // sum of minx^2
        float lossB = 0.0f;
#pragma unroll
        for (int i = 0; i < NLN; ++i)
            lossB += ws[WS_SUMY + i] /
                     (float)((const unsigned int*)ws)[WS_CNT + (i & (NBATCH - 1))];
        out[0] = (S / (float)NP + lossB) / (float)NBATCH;
    }
}

extern "C" void kernel_launch(void* const* d_in, const int* in_sizes, int n_in,
                              void* d_out, int out_size, void* d_ws, size_t ws_size,
                              hipStream_t stream) {
    const float* bins  = (const float*)d_in[0];   // [4,4,257] f32
    const float* depth = (const float*)d_in[1];   // [4,240,320] f32
    float* ws = (float*)d_ws;

    float* minabs = ws + WS_MIN;
    float* sumy   = ws + WS_SUMY;
    unsigned int* cnt = (unsigned int*)ws + WS_CNT;

    bcl_init <<<NLN * NP / BLOCK,       BLOCK, 0, stream>>>(ws);
    bcl_a    <<<NBATCH * ANCH,          BLOCK, 0, stream>>>(bins, depth, minabs);
    bcl_b    <<<NBATCH * NSCALES * BNG, BLOCK, 0, stream>>>(bins, depth, sumy, cnt);
    bcl_final<<<1,                      BLOCK, 0, stream>>>(ws, (float*)d_out);
}